// Round 14
// baseline (62.330 us; speedup 1.0000x reference)
//
#include <hip/hip_runtime.h>
#include <hip/hip_bf16.h>
#include <math.h>

#define B_ 2
#define N_ 20000
#define C_ 64
#define K_ 16
#define CS_ 16
#define EPS_ 1e-5f

typedef float f32x4_t  __attribute__((ext_vector_type(4)));
typedef short bf16x8_t __attribute__((ext_vector_type(8)));
typedef short bf16x4_t __attribute__((ext_vector_type(4)));

__device__ __forceinline__ unsigned int packbf2(float a, float b)
{
    union { __hip_bfloat162 h; unsigned int u; } cv;
    cv.h = __float22bfloat162_rn(float2{a, b});
    return cv.u;
}
__device__ __forceinline__ float bf_lo(unsigned int w)
{
    return __builtin_bit_cast(float, w << 16);
}
__device__ __forceinline__ float bf_hi(unsigned int w)
{
    return __builtin_bit_cast(float, w & 0xFFFF0000u);
}
__device__ __forceinline__ void wave_fence()
{
    __builtin_amdgcn_wave_barrier();
}

// DPP rotate-reduce over each 16-lane row (VALU pipe, not DS).
__device__ __forceinline__ float row_sum16(float x)
{
    float s = x;
    s += __builtin_bit_cast(float, __builtin_amdgcn_update_dpp(
            0, __builtin_bit_cast(int, s), 0x128, 0xF, 0xF, false)); // row_ror:8
    s += __builtin_bit_cast(float, __builtin_amdgcn_update_dpp(
            0, __builtin_bit_cast(int, s), 0x124, 0xF, 0xF, false)); // row_ror:4
    s += __builtin_bit_cast(float, __builtin_amdgcn_update_dpp(
            0, __builtin_bit_cast(int, s), 0x122, 0xF, 0xF, false)); // row_ror:2
    s += __builtin_bit_cast(float, __builtin_amdgcn_update_dpp(
            0, __builtin_bit_cast(int, s), 0x121, 0xF, 0xF, false)); // row_ror:1
    return s;
}
// Sum over a DPP quad (lanes 4k..4k+3) — pure VALU, replaces ds_bpermute shuffles.
__device__ __forceinline__ float quad_sum4(float x)
{
    float s = x;
    s += __builtin_bit_cast(float, __builtin_amdgcn_update_dpp(
            0, __builtin_bit_cast(int, s), 0xB1, 0xF, 0xF, false)); // quad_perm[1,0,3,2]
    s += __builtin_bit_cast(float, __builtin_amdgcn_update_dpp(
            0, __builtin_bit_cast(int, s), 0x4E, 0xF, 0xF, false)); // quad_perm[2,3,0,1]
    return s;
}

// ---------------------------------------------------------------------------
// Kernel A: projections + positional MLP + bn1 fold, MFMA.
// Setup kernel ELIMINATED: A-frags packed inline from raw weights
// (v_cvt_pk, ~24 VALU/wave) and epilogue constants computed per-wave;
// block 2500 instead builds attn's small tables (a1tab/a2tab/cz) — attn
// launches after proj completes, so ordering is guaranteed.
// Outputs: xq2[pt] bf16(bn1s*xq - bn1bf); kv_t[pt][c] = bf16(bn1s*(xk+pos)) | bf16(xv+pos)<<16
// ---------------------------------------------------------------------------
__global__ __launch_bounds__(256) void proj_kernel(
    const float* __restrict__ q, const float* __restrict__ kin,
    const float* __restrict__ coord,
    const float* __restrict__ wq, const float* __restrict__ wk,
    const float* __restrict__ wv,
    const float* __restrict__ bq, const float* __restrict__ bk,
    const float* __restrict__ bv,
    const float* __restrict__ p1_w, const float* __restrict__ p1_b,
    const float* __restrict__ p_bn_g, const float* __restrict__ p_bn_b,
    const float* __restrict__ p_bn_m, const float* __restrict__ p_bn_v,
    const float* __restrict__ p2_w, const float* __restrict__ p2_b,
    const float* __restrict__ w_bn1_g, const float* __restrict__ w_bn1_b,
    const float* __restrict__ w_bn1_m, const float* __restrict__ w_bn1_v,
    const float* __restrict__ w1_w, const float* __restrict__ w1_b,
    const float* __restrict__ w2_w, const float* __restrict__ w2_b,
    const float* __restrict__ w_bn2_g, const float* __restrict__ w_bn2_b,
    const float* __restrict__ w_bn2_m, const float* __restrict__ w_bn2_v,
    uint4* __restrict__ a1tab, uint2* __restrict__ a2tab,
    float* __restrict__ cz,
    unsigned int* __restrict__ xq2, unsigned int* __restrict__ kv_t)
{
    const int t = threadIdx.x;

    // ---- table-builder block for attn (runs while other blocks project) ----
    if (blockIdx.x == 2500) {
        if (t < 128) {
            int half = t >> 6, l = t & 63;
            const float* base = w1_w + (size_t)(l & 15) * C_ + half * 32 + (l >> 4) * 8;
            uint4 o;
            o.x = packbf2(base[0], base[1]); o.y = packbf2(base[2], base[3]);
            o.z = packbf2(base[4], base[5]); o.w = packbf2(base[6], base[7]);
            a1tab[t] = o;
        }
        if (t < 64) {
            const float* base = w2_w + (t & 15) * 16 + (t >> 4) * 4;
            uint2 o;
            o.x = packbf2(base[0], base[1]); o.y = packbf2(base[2], base[3]);
            a2tab[t] = o;
        }
        if (t < 16) {
            float s = w_bn2_g[t] * rsqrtf(w_bn2_v[t] + EPS_);
            cz[t]      = s;
            cz[16 + t] = (w1_b[t] - w_bn2_m[t]) * s + w_bn2_b[t];
            cz[32 + t] = w2_b[t];
        }
        return;
    }

    constexpr int PS = 26;
    __shared__ unsigned int qp[32 * PS];
    __shared__ unsigned int kp[32 * PS];

    const int og  = __builtin_amdgcn_readfirstlane(t >> 6);
    const int l   = t & 63;
    const int col = l & 15;
    const int qd  = l >> 4;
    const int pt0 = blockIdx.x * 16;
    const int pt  = pt0 + col;
    const int b   = pt0 / N_;
    const int n   = pt - b * N_;
    const size_t cb = (size_t)b * C_ * N_ + n;

    // cooperative input tile (each element loaded once per block)
#pragma unroll
    for (int r = 0; r < 2; r++) {
        int cp = (og << 3) + (qd << 1) + r;
        int ci = cp * 2;
        float q0 = q[cb + (size_t)ci * N_];
        float q1 = q[cb + (size_t)(ci + 1) * N_];
        float k0 = kin[cb + (size_t)ci * N_];
        float k1 = kin[cb + (size_t)(ci + 1) * N_];
        qp[cp * PS + col] = packbf2(q0, q1);
        kp[cp * PS + col] = packbf2(k0, k1);
    }

    // A-fragments packed inline from raw weights (row = og*16+col)
    union bf8u { bf16x8_t v; uint4 u4; unsigned int u[4]; };
    const int arow = og * 16 + col;
    bf8u awq[2], awk[2], awv[2];
#pragma unroll
    for (int half = 0; half < 2; half++) {
        const float* wqb = wq + (size_t)arow * C_ + half * 32 + qd * 8;
        const float* wkb = wk + (size_t)arow * C_ + half * 32 + qd * 8;
        const float* wvb = wv + (size_t)arow * C_ + half * 32 + qd * 8;
        float4 f0, f1;
        f0 = *reinterpret_cast<const float4*>(wqb);
        f1 = *reinterpret_cast<const float4*>(wqb + 4);
        awq[half].u4 = uint4{packbf2(f0.x, f0.y), packbf2(f0.z, f0.w),
                             packbf2(f1.x, f1.y), packbf2(f1.z, f1.w)};
        f0 = *reinterpret_cast<const float4*>(wkb);
        f1 = *reinterpret_cast<const float4*>(wkb + 4);
        awk[half].u4 = uint4{packbf2(f0.x, f0.y), packbf2(f0.z, f0.w),
                             packbf2(f1.x, f1.y), packbf2(f1.z, f1.w)};
        f0 = *reinterpret_cast<const float4*>(wvb);
        f1 = *reinterpret_cast<const float4*>(wvb + 4);
        awv[half].u4 = uint4{packbf2(f0.x, f0.y), packbf2(f0.z, f0.w),
                             packbf2(f1.x, f1.y), packbf2(f1.z, f1.w)};
    }

    __syncthreads();

    bf8u bq_[2], bk_[2];
#pragma unroll
    for (int half = 0; half < 2; half++) {
#pragma unroll
        for (int i2 = 0; i2 < 4; i2++) {
            int cp = half * 16 + qd * 4 + i2;
            bq_[half].u[i2] = qp[cp * PS + col];
            bk_[half].u[i2] = kp[cp * PS + col];
        }
    }

    f32x4_t uq = {0.f, 0.f, 0.f, 0.f};
    f32x4_t uv = {0.f, 0.f, 0.f, 0.f};
    f32x4_t uk = {0.f, 0.f, 0.f, 0.f};
    uq = __builtin_amdgcn_mfma_f32_16x16x32_bf16(awq[0].v, bq_[0].v, uq, 0, 0, 0);
    uq = __builtin_amdgcn_mfma_f32_16x16x32_bf16(awq[1].v, bq_[1].v, uq, 0, 0, 0);
    uv = __builtin_amdgcn_mfma_f32_16x16x32_bf16(awv[0].v, bq_[0].v, uv, 0, 0, 0);
    uv = __builtin_amdgcn_mfma_f32_16x16x32_bf16(awv[1].v, bq_[1].v, uv, 0, 0, 0);
    uk = __builtin_amdgcn_mfma_f32_16x16x32_bf16(awk[0].v, bk_[0].v, uk, 0, 0, 0);
    uk = __builtin_amdgcn_mfma_f32_16x16x32_bf16(awk[1].v, bk_[1].v, uk, 0, 0, 0);

    // positional MLP layer 1 (wave-uniform weights -> s_loads)
    float pbs[3], pbb[3];
#pragma unroll
    for (int j = 0; j < 3; j++) {
        float s = p_bn_g[j] * rsqrtf(p_bn_v[j] + EPS_);
        pbs[j] = s;
        pbb[j] = (p1_b[j] - p_bn_m[j]) * s + p_bn_b[j];
    }
    float cx = coord[pt * 3 + 0], cy = coord[pt * 3 + 1], cz_ = coord[pt * 3 + 2];
    float h0 = fmaxf(0.f, (p1_w[0]*cx + p1_w[1]*cy + p1_w[2]*cz_) * pbs[0] + pbb[0]);
    float h1 = fmaxf(0.f, (p1_w[3]*cx + p1_w[4]*cy + p1_w[5]*cz_) * pbs[1] + pbb[1]);
    float h2 = fmaxf(0.f, (p1_w[6]*cx + p1_w[7]*cy + p1_w[8]*cz_) * pbs[2] + pbb[2]);

    // epilogue constants inline (all 16B-aligned vector loads)
    const int ch0 = og * 16 + qd * 4;
    const float4 g1  = *reinterpret_cast<const float4*>(w_bn1_g + ch0);
    const float4 b1  = *reinterpret_cast<const float4*>(w_bn1_b + ch0);
    const float4 m1  = *reinterpret_cast<const float4*>(w_bn1_m + ch0);
    const float4 v1  = *reinterpret_cast<const float4*>(w_bn1_v + ch0);
    const float4 bqv = *reinterpret_cast<const float4*>(bq + ch0);
    const float4 bkv = *reinterpret_cast<const float4*>(bk + ch0);
    const float4 bvv = *reinterpret_cast<const float4*>(bv + ch0);
    const float4 pw0 = *reinterpret_cast<const float4*>(p2_w + (size_t)ch0 * 3);
    const float4 pw1 = *reinterpret_cast<const float4*>(p2_w + (size_t)ch0 * 3 + 4);
    const float4 pw2 = *reinterpret_cast<const float4*>(p2_w + (size_t)ch0 * 3 + 8);
    const float4 pb4 = *reinterpret_cast<const float4*>(p2_b + ch0);

    float pos[4];
    pos[0] = fmaf(pw0.x, h0, fmaf(pw0.y, h1, fmaf(pw0.z, h2, pb4.x)));
    pos[1] = fmaf(pw0.w, h0, fmaf(pw1.x, h1, fmaf(pw1.y, h2, pb4.y)));
    pos[2] = fmaf(pw1.z, h0, fmaf(pw1.w, h1, fmaf(pw2.x, h2, pb4.z)));
    pos[3] = fmaf(pw2.y, h0, fmaf(pw2.z, h1, fmaf(pw2.w, h2, pb4.w)));

    float xv2[4];
    uint4 kvo;
#pragma unroll
    for (int rr = 0; rr < 4; rr++) {
        float s   = (&g1.x)[rr] * rsqrtf((&v1.x)[rr] + EPS_);
        float b1f = (&b1.x)[rr] - (&m1.x)[rr] * s;
        xv2[rr]   = s * (uq[rr] + (&bqv.x)[rr]) - b1f;
        float kk  = s * (uk[rr] + (&bkv.x)[rr] + pos[rr]);
        float vv  = uv[rr] + (&bvv.x)[rr] + pos[rr];
        (&kvo.x)[rr] = packbf2(kk, vv);
    }
    uint2 xqo;
    xqo.x = packbf2(xv2[0], xv2[1]);
    xqo.y = packbf2(xv2[2], xv2[3]);
    *reinterpret_cast<uint2*>(xq2 + (size_t)pt * 32 + (ch0 >> 1)) = xqo;
    *reinterpret_cast<uint4*>(kv_t + (size_t)pt * C_ + ch0) = kvo;
}

// ---------------------------------------------------------------------------
// Kernel B: attention via MFMA — DS-lean, quad-perm phase-3 reduce.
// Block = 512 thr = 8 waves = 8 points.
// Phase1/3 roles: cquad = l>>2 (4 channels c0 = 4*cquad), kq = l&3
//   (4 neighbors k = 4*kq+j): 4x dwordx4 gathers, 4x ds_write_b64.
// Phase2 roles (al = l&15, qd = l>>4): 2x mfma 16x16x32, bn2/relu in regs,
//   1x mfma 16x16x16; softmax via DPP row_ror rotate-reduce.
// Phase3: 4x ds_read_b128 sfb rows, quad_perm DPP sum (VALU — the 4 partial
//   lanes sit in one DPP quad), kq==0 lanes write the out tile.
// DS ops/wave ~13. LDS 30848B -> 4 blocks/CU = 32 waves/CU.
// ---------------------------------------------------------------------------
#define WROW 72          // ushorts per w-tile row (144B)
#define WPN  (K_ * WROW) // 1152 per point
#define SS4  20          // sfb row stride (f32)
#define SPN  (K_ * SS4)  // 320 per point
#define OS   68          // otile row stride (f32)

__global__ __launch_bounds__(512, 8) void attn_kernel(
    const int* __restrict__ nbr,
    const unsigned int* __restrict__ xq2, const unsigned int* __restrict__ kv_t,
    const uint4* __restrict__ a1tab, const uint2* __restrict__ a2tab,
    const float* __restrict__ cz,
    float* __restrict__ out)
{
    __shared__ unsigned short wlds_all[8 * WPN];   // 18432B
    __shared__ float          sfb_all[8 * SPN];    // 10240B
    __shared__ float          otile[8 * OS];       //  2176B

    const int t  = threadIdx.x;
    const int w  = __builtin_amdgcn_readfirstlane(t >> 6);
    const int l  = t & 63;
    const int al = l & 15;          // phase-2 roles
    const int qd = l >> 4;
    const int cquad = l >> 2;       // phase-1/3: 4 channels c0..c0+3
    const int kq    = l & 3;        // phase-1/3: 4 neighbors 4kq..4kq+3
    const int c0    = cquad * 4;
    const int g0    = c0 & 15;

    const int pt0 = blockIdx.x * 8;       // 5000 blocks; 20000%8==0, no straddle
    const int b   = pt0 / N_;
    const int bB  = b * N_;
    const int bn  = pt0 + w;

    unsigned short* wlds = wlds_all + w * WPN;
    float*          sfb  = sfb_all + w * SPN;

    // ---- phase 1: gather 4 neighbors x 4 channels (dwordx4, 16B/lane) ----
    const int* nb = nbr + (size_t)bn * K_;
    uint4 kvw[4];
#pragma unroll
    for (int j = 0; j < 4; j++) {
        int idx = nb[kq * 4 + j];
        kvw[j] = *reinterpret_cast<const uint4*>(kv_t + ((size_t)(bB + idx) * C_ + c0));
    }
    const uint2 xqu = *reinterpret_cast<const uint2*>(xq2 + (size_t)bn * 32 + (c0 >> 1));
    const float xqa = bf_lo(xqu.x), xqb = bf_hi(xqu.x);
    const float xqc = bf_lo(xqu.y), xqd = bf_hi(xqu.y);

    // constants from tables
    union bf8u { bf16x8_t v; uint4 u4; };
    union bf4u { bf16x4_t v; uint2 u2; };
    bf8u a1q0, a1q1; bf4u a2q;
    a1q0.u4 = a1tab[l];
    a1q1.u4 = a1tab[64 + l];
    a2q.u2  = a2tab[l];
    const float4 zsc4 = *reinterpret_cast<const float4*>(cz + qd * 4);
    const float4 zbi4 = *reinterpret_cast<const float4*>(cz + 16 + qd * 4);
    const float4 tbi4 = *reinterpret_cast<const float4*>(cz + 32 + qd * 4);

    // w = relu(kvlo - xq2), packed pairs -> one ds_write_b64 per neighbor
#pragma unroll
    for (int j = 0; j < 4; j++) {
        float w0 = fmaxf(0.f, bf_lo(kvw[j].x) - xqa);
        float w1 = fmaxf(0.f, bf_lo(kvw[j].y) - xqb);
        float w2 = fmaxf(0.f, bf_lo(kvw[j].z) - xqc);
        float w3 = fmaxf(0.f, bf_lo(kvw[j].w) - xqd);
        uint2 wpk;
        wpk.x = packbf2(w0, w1);
        wpk.y = packbf2(w2, w3);
        *reinterpret_cast<uint2*>(wlds + (kq * 4 + j) * WROW + c0) = wpk;
    }
    wave_fence();

    // ---- phase 2a: u = w1 @ w^T ----
    const bf16x8_t b0 = *reinterpret_cast<const bf16x8_t*>(wlds + al * WROW + qd * 8);
    const bf16x8_t b1 = *reinterpret_cast<const bf16x8_t*>(wlds + al * WROW + 32 + qd * 8);
    f32x4_t u = {0.f, 0.f, 0.f, 0.f};
    u = __builtin_amdgcn_mfma_f32_16x16x32_bf16(a1q0.v, b0, u, 0, 0, 0);
    u = __builtin_amdgcn_mfma_f32_16x16x32_bf16(a1q1.v, b1, u, 0, 0, 0);

    union { bf16x4_t v; unsigned int u2[2]; } zb;
    {
        float z0 = fmaxf(0.f, u[0] * zsc4.x + zbi4.x);
        float z1 = fmaxf(0.f, u[1] * zsc4.y + zbi4.y);
        float z2 = fmaxf(0.f, u[2] * zsc4.z + zbi4.z);
        float z3 = fmaxf(0.f, u[3] * zsc4.w + zbi4.w);
        zb.u2[0] = packbf2(z0, z1);
        zb.u2[1] = packbf2(z2, z3);
    }

    // ---- phase 2b: t = w2 @ z ----
    f32x4_t t4 = {0.f, 0.f, 0.f, 0.f};
    t4 = __builtin_amdgcn_mfma_f32_16x16x16bf16_1k(a2q.v, zb.v, t4, 0, 0, 0);

    // ---- softmax over neighbors: DPP rotate-reduce (VALU) ----
    float4 sv;
#pragma unroll
    for (int rr = 0; rr < 4; rr++) {
        float e = __expf(t4[rr] + (&tbi4.x)[rr]);   // |t| << 80, no max-sub
        float s = row_sum16(e);
        (&sv.x)[rr] = e * __builtin_amdgcn_rcpf(s);
    }
    *reinterpret_cast<float4*>(sfb + al * SS4 + qd * 4) = sv;  // [k][g] row al
    wave_fence();

    // ---- phase 3: out[c] = sum_k v[k][c] * soft[k][c&15] ----
    float acc[4] = {0.f, 0.f, 0.f, 0.f};
#pragma unroll
    for (int j = 0; j < 4; j++) {
        const float4 sp = *reinterpret_cast<const float4*>(sfb + (kq * 4 + j) * SS4 + g0);
        acc[0] = fmaf(bf_hi(kvw[j].x), sp.x, acc[0]);
        acc[1] = fmaf(bf_hi(kvw[j].y), sp.y, acc[1]);
        acc[2] = fmaf(bf_hi(kvw[j].z), sp.z, acc[2]);
        acc[3] = fmaf(bf_hi(kvw[j].w), sp.w, acc[3]);
    }
#pragma unroll
    for (int i = 0; i < 4; i++)
        acc[i] = quad_sum4(acc[i]);     // sum over the 4 kq lanes (one DPP quad)
    if (kq == 0) {
        float4 o4 = float4{acc[0], acc[1], acc[2], acc[3]};
        *reinterpret_cast<float4*>(otile + w * OS + c0) = o4;
    }
    __syncthreads();

    // coalesced [B,C,N] write: thread t -> (c = t>>3, n = pt0%N + (t&7))
    {
        int c  = t >> 3;
        int nn = t & 7;
        out[(size_t)b * C_ * N_ + (size_t)c * N_ + (pt0 - bB) + nn] = otile[nn * OS + c];
    }
}

// ---------------------------------------------------------------------------
extern "C" void kernel_launch(void* const* d_in, const int* in_sizes, int n_in,
                              void* d_out, int out_size, void* d_ws, size_t ws_size,
                              hipStream_t stream)
{
    const float* coord = (const float*)d_in[0];
    const float* q     = (const float*)d_in[1];
    const float* k     = (const float*)d_in[2];
    const int*   nbr   = (const int*)d_in[3];
    const float* wq = (const float*)d_in[4];
    const float* bq = (const float*)d_in[5];
    const float* wk = (const float*)d_in[6];
    const float* bk = (const float*)d_in[7];
    const float* wv = (const float*)d_in[8];
    const float* bv = (const float*)d_in[9];
    const float* p1_w = (const float*)d_in[10];
    const float* p1_b = (const float*)d_in[11];
    const float* p_bn_g = (const float*)d_in[12];
    const float* p_bn_b = (const float*)d_in[13];
    const float* p_bn_m = (const float*)d_in[14];
    const float* p_bn_v = (const float*)d_in[15];
    const float* p2_w = (const float*)d_in[16];
    const float* p2_b = (const float*)d_in[17];
    const float* w_bn1_g = (const float*)d_in[18];
    const float* w_bn1_b = (const float*)d_in[19];
    const float* w_bn1_m = (const float*)d_in[20];
    const float* w_bn1_v = (const float*)d_in[21];
    const float* w1_w = (const float*)d_in[22];
    const float* w1_b = (const float*)d_in[23];
    const float* w_bn2_g = (const float*)d_in[24];
    const float* w_bn2_b = (const float*)d_in[25];
    const float* w_bn2_m = (const float*)d_in[26];
    const float* w_bn2_v = (const float*)d_in[27];
    const float* w2_w = (const float*)d_in[28];
    const float* w2_b = (const float*)d_in[29];

    const size_t PTS = (size_t)B_ * N_;        // 40000
    char* wsb = (char*)d_ws;
    unsigned int* kv_t = (unsigned int*)wsb;                    // [PTS][64] u32 (10.24MB)
    unsigned int* xq2  = (unsigned int*)(wsb + PTS * C_ * 4);   // [PTS][32] u32 (5.12MB)
    uint4* a1tab = (uint4*)(wsb + PTS * C_ * 4 + PTS * C_ * 2); // 128 uint4
    uint2* a2tab = (uint2*)(a1tab + 128);                       // 64 uint2
    float* cz    = (float*)(a2tab + 64);                        // 48 f32

    // 2500 proj blocks + 1 table-builder block for attn
    proj_kernel<<<2501, 256, 0, stream>>>(
        q, k, coord, wq, wk, wv, bq, bk, bv,
        p1_w, p1_b, p_bn_g, p_bn_b, p_bn_m, p_bn_v, p2_w, p2_b,
        w_bn1_g, w_bn1_b, w_bn1_m, w_bn1_v,
        w1_w, w1_b, w2_w, w2_b,
        w_bn2_g, w_bn2_b, w_bn2_m, w_bn2_v,
        a1tab, a2tab, cz, xq2, kv_t);

    attn_kernel<<<(B_ * N_) / 8, 512, 0, stream>>>(
        nbr, xq2, kv_t, a1tab, a2tab, cz,
        (float*)d_out);
}

// Round 15
// 52.077 us; speedup vs baseline: 1.1969x; 1.1969x over previous
//
#include <hip/hip_runtime.h>
#include <hip/hip_bf16.h>
#include <math.h>

#define B_ 2
#define N_ 20000
#define C_ 64
#define K_ 16
#define CS_ 16
#define EPS_ 1e-5f

typedef float f32x4_t  __attribute__((ext_vector_type(4)));
typedef short bf16x8_t __attribute__((ext_vector_type(8)));
typedef short bf16x4_t __attribute__((ext_vector_type(4)));

__device__ __forceinline__ unsigned int packbf2(float a, float b)
{
    union { __hip_bfloat162 h; unsigned int u; } cv;
    cv.h = __float22bfloat162_rn(float2{a, b});
    return cv.u;
}
__device__ __forceinline__ float bf_lo(unsigned int w)
{
    return __builtin_bit_cast(float, w << 16);
}
__device__ __forceinline__ float bf_hi(unsigned int w)
{
    return __builtin_bit_cast(float, w & 0xFFFF0000u);
}
__device__ __forceinline__ void wave_fence()
{
    __builtin_amdgcn_wave_barrier();
}

// DPP rotate-reduce over each 16-lane row (VALU pipe, not DS).
__device__ __forceinline__ float row_sum16(float x)
{
    float s = x;
    s += __builtin_bit_cast(float, __builtin_amdgcn_update_dpp(
            0, __builtin_bit_cast(int, s), 0x128, 0xF, 0xF, false)); // row_ror:8
    s += __builtin_bit_cast(float, __builtin_amdgcn_update_dpp(
            0, __builtin_bit_cast(int, s), 0x124, 0xF, 0xF, false)); // row_ror:4
    s += __builtin_bit_cast(float, __builtin_amdgcn_update_dpp(
            0, __builtin_bit_cast(int, s), 0x122, 0xF, 0xF, false)); // row_ror:2
    s += __builtin_bit_cast(float, __builtin_amdgcn_update_dpp(
            0, __builtin_bit_cast(int, s), 0x121, 0xF, 0xF, false)); // row_ror:1
    return s;
}

// ---------------------------------------------------------------------------
// Kernel A: projections + positional MLP + bn1 fold, MFMA.
// Setup kernel eliminated: A-frags packed inline from raw (L2-hot) weights;
// block 2500 builds attn's small tables (a1tab/a2tab/cz). attn launches
// after proj completes -> ordering guaranteed by stream serialization.
// Outputs: xq2[pt] bf16(bn1s*xq - bn1bf);
//          kv_t[pt][c] = bf16(bn1s*(xk+pos)) | bf16(xv+pos)<<16
// ---------------------------------------------------------------------------
__global__ __launch_bounds__(256) void proj_kernel(
    const float* __restrict__ q, const float* __restrict__ kin,
    const float* __restrict__ coord,
    const float* __restrict__ wq, const float* __restrict__ wk,
    const float* __restrict__ wv,
    const float* __restrict__ bq, const float* __restrict__ bk,
    const float* __restrict__ bv,
    const float* __restrict__ p1_w, const float* __restrict__ p1_b,
    const float* __restrict__ p_bn_g, const float* __restrict__ p_bn_b,
    const float* __restrict__ p_bn_m, const float* __restrict__ p_bn_v,
    const float* __restrict__ p2_w, const float* __restrict__ p2_b,
    const float* __restrict__ w_bn1_g, const float* __restrict__ w_bn1_b,
    const float* __restrict__ w_bn1_m, const float* __restrict__ w_bn1_v,
    const float* __restrict__ w1_w, const float* __restrict__ w1_b,
    const float* __restrict__ w2_w, const float* __restrict__ w2_b,
    const float* __restrict__ w_bn2_g, const float* __restrict__ w_bn2_b,
    const float* __restrict__ w_bn2_m, const float* __restrict__ w_bn2_v,
    uint4* __restrict__ a1tab, uint2* __restrict__ a2tab,
    float* __restrict__ cz,
    unsigned int* __restrict__ xq2, unsigned int* __restrict__ kv_t)
{
    const int t = threadIdx.x;

    // ---- table-builder block for attn (runs while other blocks project) ----
    if (blockIdx.x == 2500) {
        if (t < 128) {
            int half = t >> 6, l = t & 63;
            const float* base = w1_w + (size_t)(l & 15) * C_ + half * 32 + (l >> 4) * 8;
            uint4 o;
            o.x = packbf2(base[0], base[1]); o.y = packbf2(base[2], base[3]);
            o.z = packbf2(base[4], base[5]); o.w = packbf2(base[6], base[7]);
            a1tab[t] = o;
        }
        if (t < 64) {
            const float* base = w2_w + (t & 15) * 16 + (t >> 4) * 4;
            uint2 o;
            o.x = packbf2(base[0], base[1]); o.y = packbf2(base[2], base[3]);
            a2tab[t] = o;
        }
        if (t < 16) {
            float s = w_bn2_g[t] * rsqrtf(w_bn2_v[t] + EPS_);
            cz[t]      = s;
            cz[16 + t] = (w1_b[t] - w_bn2_m[t]) * s + w_bn2_b[t];
            cz[32 + t] = w2_b[t];
        }
        return;
    }

    constexpr int PS = 26;
    __shared__ unsigned int qp[32 * PS];
    __shared__ unsigned int kp[32 * PS];

    const int og  = __builtin_amdgcn_readfirstlane(t >> 6);
    const int l   = t & 63;
    const int col = l & 15;
    const int qd  = l >> 4;
    const int pt0 = blockIdx.x * 16;
    const int pt  = pt0 + col;
    const int b   = pt0 / N_;
    const int n   = pt - b * N_;
    const size_t cb = (size_t)b * C_ * N_ + n;

    // cooperative input tile (each element loaded once per block)
#pragma unroll
    for (int r = 0; r < 2; r++) {
        int cp = (og << 3) + (qd << 1) + r;
        int ci = cp * 2;
        float q0 = q[cb + (size_t)ci * N_];
        float q1 = q[cb + (size_t)(ci + 1) * N_];
        float k0 = kin[cb + (size_t)ci * N_];
        float k1 = kin[cb + (size_t)(ci + 1) * N_];
        qp[cp * PS + col] = packbf2(q0, q1);
        kp[cp * PS + col] = packbf2(k0, k1);
    }

    // A-fragments packed inline from raw weights (row = og*16+col)
    union bf8u { bf16x8_t v; uint4 u4; unsigned int u[4]; };
    const int arow = og * 16 + col;
    bf8u awq[2], awk[2], awv[2];
#pragma unroll
    for (int half = 0; half < 2; half++) {
        const float* wqb = wq + (size_t)arow * C_ + half * 32 + qd * 8;
        const float* wkb = wk + (size_t)arow * C_ + half * 32 + qd * 8;
        const float* wvb = wv + (size_t)arow * C_ + half * 32 + qd * 8;
        float4 f0, f1;
        f0 = *reinterpret_cast<const float4*>(wqb);
        f1 = *reinterpret_cast<const float4*>(wqb + 4);
        awq[half].u4 = uint4{packbf2(f0.x, f0.y), packbf2(f0.z, f0.w),
                             packbf2(f1.x, f1.y), packbf2(f1.z, f1.w)};
        f0 = *reinterpret_cast<const float4*>(wkb);
        f1 = *reinterpret_cast<const float4*>(wkb + 4);
        awk[half].u4 = uint4{packbf2(f0.x, f0.y), packbf2(f0.z, f0.w),
                             packbf2(f1.x, f1.y), packbf2(f1.z, f1.w)};
        f0 = *reinterpret_cast<const float4*>(wvb);
        f1 = *reinterpret_cast<const float4*>(wvb + 4);
        awv[half].u4 = uint4{packbf2(f0.x, f0.y), packbf2(f0.z, f0.w),
                             packbf2(f1.x, f1.y), packbf2(f1.z, f1.w)};
    }

    __syncthreads();

    bf8u bq_[2], bk_[2];
#pragma unroll
    for (int half = 0; half < 2; half++) {
#pragma unroll
        for (int i2 = 0; i2 < 4; i2++) {
            int cp = half * 16 + qd * 4 + i2;
            bq_[half].u[i2] = qp[cp * PS + col];
            bk_[half].u[i2] = kp[cp * PS + col];
        }
    }

    f32x4_t uq = {0.f, 0.f, 0.f, 0.f};
    f32x4_t uv = {0.f, 0.f, 0.f, 0.f};
    f32x4_t uk = {0.f, 0.f, 0.f, 0.f};
    uq = __builtin_amdgcn_mfma_f32_16x16x32_bf16(awq[0].v, bq_[0].v, uq, 0, 0, 0);
    uq = __builtin_amdgcn_mfma_f32_16x16x32_bf16(awq[1].v, bq_[1].v, uq, 0, 0, 0);
    uv = __builtin_amdgcn_mfma_f32_16x16x32_bf16(awv[0].v, bq_[0].v, uv, 0, 0, 0);
    uv = __builtin_amdgcn_mfma_f32_16x16x32_bf16(awv[1].v, bq_[1].v, uv, 0, 0, 0);
    uk = __builtin_amdgcn_mfma_f32_16x16x32_bf16(awk[0].v, bk_[0].v, uk, 0, 0, 0);
    uk = __builtin_amdgcn_mfma_f32_16x16x32_bf16(awk[1].v, bk_[1].v, uk, 0, 0, 0);

    // positional MLP layer 1 (wave-uniform weights -> s_loads)
    float pbs[3], pbb[3];
#pragma unroll
    for (int j = 0; j < 3; j++) {
        float s = p_bn_g[j] * rsqrtf(p_bn_v[j] + EPS_);
        pbs[j] = s;
        pbb[j] = (p1_b[j] - p_bn_m[j]) * s + p_bn_b[j];
    }
    float cx = coord[pt * 3 + 0], cy = coord[pt * 3 + 1], cz_ = coord[pt * 3 + 2];
    float h0 = fmaxf(0.f, (p1_w[0]*cx + p1_w[1]*cy + p1_w[2]*cz_) * pbs[0] + pbb[0]);
    float h1 = fmaxf(0.f, (p1_w[3]*cx + p1_w[4]*cy + p1_w[5]*cz_) * pbs[1] + pbb[1]);
    float h2 = fmaxf(0.f, (p1_w[6]*cx + p1_w[7]*cy + p1_w[8]*cz_) * pbs[2] + pbb[2]);

    // epilogue constants inline (16B-aligned vector loads, L2-hot)
    const int ch0 = og * 16 + qd * 4;
    const float4 g1  = *reinterpret_cast<const float4*>(w_bn1_g + ch0);
    const float4 b1  = *reinterpret_cast<const float4*>(w_bn1_b + ch0);
    const float4 m1  = *reinterpret_cast<const float4*>(w_bn1_m + ch0);
    const float4 v1  = *reinterpret_cast<const float4*>(w_bn1_v + ch0);
    const float4 bqv = *reinterpret_cast<const float4*>(bq + ch0);
    const float4 bkv = *reinterpret_cast<const float4*>(bk + ch0);
    const float4 bvv = *reinterpret_cast<const float4*>(bv + ch0);
    const float4 pw0 = *reinterpret_cast<const float4*>(p2_w + (size_t)ch0 * 3);
    const float4 pw1 = *reinterpret_cast<const float4*>(p2_w + (size_t)ch0 * 3 + 4);
    const float4 pw2 = *reinterpret_cast<const float4*>(p2_w + (size_t)ch0 * 3 + 8);
    const float4 pb4 = *reinterpret_cast<const float4*>(p2_b + ch0);

    float pos[4];
    pos[0] = fmaf(pw0.x, h0, fmaf(pw0.y, h1, fmaf(pw0.z, h2, pb4.x)));
    pos[1] = fmaf(pw0.w, h0, fmaf(pw1.x, h1, fmaf(pw1.y, h2, pb4.y)));
    pos[2] = fmaf(pw1.z, h0, fmaf(pw1.w, h1, fmaf(pw2.x, h2, pb4.z)));
    pos[3] = fmaf(pw2.y, h0, fmaf(pw2.z, h1, fmaf(pw2.w, h2, pb4.w)));

    float xv2[4];
    uint4 kvo;
#pragma unroll
    for (int rr = 0; rr < 4; rr++) {
        float s   = (&g1.x)[rr] * rsqrtf((&v1.x)[rr] + EPS_);
        float b1f = (&b1.x)[rr] - (&m1.x)[rr] * s;
        xv2[rr]   = s * (uq[rr] + (&bqv.x)[rr]) - b1f;
        float kk  = s * (uk[rr] + (&bkv.x)[rr] + pos[rr]);
        float vv  = uv[rr] + (&bvv.x)[rr] + pos[rr];
        (&kvo.x)[rr] = packbf2(kk, vv);
    }
    uint2 xqo;
    xqo.x = packbf2(xv2[0], xv2[1]);
    xqo.y = packbf2(xv2[2], xv2[3]);
    *reinterpret_cast<uint2*>(xq2 + (size_t)pt * 32 + (ch0 >> 1)) = xqo;
    *reinterpret_cast<uint4*>(kv_t + (size_t)pt * C_ + ch0) = kvo;
}

// ---------------------------------------------------------------------------
// Kernel B: attention via MFMA — exact R13 structure (coalesced roles).
// Block = 512 thr = 8 waves = 8 points.
// Phase1/3 roles: cquad = l&15 (4 channels c0=4*cquad), kq = l>>4
//   (4 neighbors k = 4*kq+j): lanes 0-15 read ONE neighbor row contiguously
//   -> 4x 256B coalesced segments per gather instruction. 4x ds_write_b64.
// Phase2 roles (al = l&15, qd = l>>4): 2x mfma 16x16x32, bn2/relu in regs,
//   1x mfma 16x16x16; softmax via DPP row_ror rotate-reduce (VALU).
// Phase3: 4x ds_read_b128 sfb rows, shfl_xor(16/32) combine, kq==0 writes.
// LDS 30848B -> 4 blocks/CU = 32 waves/CU.
// ---------------------------------------------------------------------------
#define WROW 72          // ushorts per w-tile row (144B)
#define WPN  (K_ * WROW) // 1152 per point
#define SS4  20          // sfb row stride (f32)
#define SPN  (K_ * SS4)  // 320 per point
#define OS   68          // otile row stride (f32)

__global__ __launch_bounds__(512, 8) void attn_kernel(
    const int* __restrict__ nbr,
    const unsigned int* __restrict__ xq2, const unsigned int* __restrict__ kv_t,
    const uint4* __restrict__ a1tab, const uint2* __restrict__ a2tab,
    const float* __restrict__ cz,
    float* __restrict__ out)
{
    __shared__ unsigned short wlds_all[8 * WPN];   // 18432B
    __shared__ float          sfb_all[8 * SPN];    // 10240B
    __shared__ float          otile[8 * OS];       //  2176B

    const int t  = threadIdx.x;
    const int w  = __builtin_amdgcn_readfirstlane(t >> 6);
    const int l  = t & 63;
    const int al = l & 15;          // phase-2 / channel-quad role
    const int qd = l >> 4;          // phase-2 row-quad / neighbor-quad role
    const int cquad = al;           // phase-1/3: 4 channels c0..c0+3
    const int kq    = qd;           // phase-1/3: 4 neighbors 4kq..4kq+3
    const int c0    = cquad * 4;
    const int g0    = c0 & 15;

    const int pt0 = blockIdx.x * 8;       // 5000 blocks; 20000%8==0, no straddle
    const int b   = pt0 / N_;
    const int bB  = b * N_;
    const int bn  = pt0 + w;

    unsigned short* wlds = wlds_all + w * WPN;
    float*          sfb  = sfb_all + w * SPN;

    // ---- phase 1: gather 4 neighbors x 4 channels (dwordx4, 16B/lane) ----
    const int* nb = nbr + (size_t)bn * K_;
    uint4 kvw[4];
#pragma unroll
    for (int j = 0; j < 4; j++) {
        int idx = nb[kq * 4 + j];          // wave-uniform -> s_load
        kvw[j] = *reinterpret_cast<const uint4*>(kv_t + ((size_t)(bB + idx) * C_ + c0));
    }
    const uint2 xqu = *reinterpret_cast<const uint2*>(xq2 + (size_t)bn * 32 + (c0 >> 1));
    const float xqa = bf_lo(xqu.x), xqb = bf_hi(xqu.x);
    const float xqc = bf_lo(xqu.y), xqd = bf_hi(xqu.y);

    // constants from tables
    union bf8u { bf16x8_t v; uint4 u4; };
    union bf4u { bf16x4_t v; uint2 u2; };
    bf8u a1q0, a1q1; bf4u a2q;
    a1q0.u4 = a1tab[l];
    a1q1.u4 = a1tab[64 + l];
    a2q.u2  = a2tab[l];
    const float4 zsc4 = *reinterpret_cast<const float4*>(cz + qd * 4);
    const float4 zbi4 = *reinterpret_cast<const float4*>(cz + 16 + qd * 4);
    const float4 tbi4 = *reinterpret_cast<const float4*>(cz + 32 + qd * 4);

    // w = relu(kvlo - xq2), packed pairs -> one ds_write_b64 per neighbor
#pragma unroll
    for (int j = 0; j < 4; j++) {
        float w0 = fmaxf(0.f, bf_lo(kvw[j].x) - xqa);
        float w1 = fmaxf(0.f, bf_lo(kvw[j].y) - xqb);
        float w2 = fmaxf(0.f, bf_lo(kvw[j].z) - xqc);
        float w3 = fmaxf(0.f, bf_lo(kvw[j].w) - xqd);
        uint2 wpk;
        wpk.x = packbf2(w0, w1);
        wpk.y = packbf2(w2, w3);
        *reinterpret_cast<uint2*>(wlds + (kq * 4 + j) * WROW + c0) = wpk;
    }
    wave_fence();

    // ---- phase 2a: u = w1 @ w^T ----
    const bf16x8_t b0 = *reinterpret_cast<const bf16x8_t*>(wlds + al * WROW + qd * 8);
    const bf16x8_t b1 = *reinterpret_cast<const bf16x8_t*>(wlds + al * WROW + 32 + qd * 8);
    f32x4_t u = {0.f, 0.f, 0.f, 0.f};
    u = __builtin_amdgcn_mfma_f32_16x16x32_bf16(a1q0.v, b0, u, 0, 0, 0);
    u = __builtin_amdgcn_mfma_f32_16x16x32_bf16(a1q1.v, b1, u, 0, 0, 0);

    union { bf16x4_t v; unsigned int u2[2]; } zb;
    {
        float z0 = fmaxf(0.f, u[0] * zsc4.x + zbi4.x);
        float z1 = fmaxf(0.f, u[1] * zsc4.y + zbi4.y);
        float z2 = fmaxf(0.f, u[2] * zsc4.z + zbi4.z);
        float z3 = fmaxf(0.f, u[3] * zsc4.w + zbi4.w);
        zb.u2[0] = packbf2(z0, z1);
        zb.u2[1] = packbf2(z2, z3);
    }

    // ---- phase 2b: t = w2 @ z ----
    f32x4_t t4 = {0.f, 0.f, 0.f, 0.f};
    t4 = __builtin_amdgcn_mfma_f32_16x16x16bf16_1k(a2q.v, zb.v, t4, 0, 0, 0);

    // ---- softmax over neighbors: DPP rotate-reduce (VALU) ----
    float4 sv;
#pragma unroll
    for (int rr = 0; rr < 4; rr++) {
        float e = __expf(t4[rr] + (&tbi4.x)[rr]);   // |t| << 80, no max-sub
        float s = row_sum16(e);
        (&sv.x)[rr] = e * __builtin_amdgcn_rcpf(s);
    }
    *reinterpret_cast<float4*>(sfb + al * SS4 + qd * 4) = sv;  // [k][g] row al
    wave_fence();

    // ---- phase 3: out[c] = sum_k v[k][c] * soft[k][c&15] ----
    float acc[4] = {0.f, 0.f, 0.f, 0.f};
#pragma unroll
    for (int j = 0; j < 4; j++) {
        const float4 sp = *reinterpret_cast<const float4*>(sfb + (kq * 4 + j) * SS4 + g0);
        acc[0] = fmaf(bf_hi(kvw[j].x), sp.x, acc[0]);
        acc[1] = fmaf(bf_hi(kvw[j].y), sp.y, acc[1]);
        acc[2] = fmaf(bf_hi(kvw[j].z), sp.z, acc[2]);
        acc[3] = fmaf(bf_hi(kvw[j].w), sp.w, acc[3]);
    }
#pragma unroll
    for (int i = 0; i < 4; i++) {
        acc[i] += __shfl_xor(acc[i], 16);
        acc[i] += __shfl_xor(acc[i], 32);
    }
    if (kq == 0) {
        float4 o4 = float4{acc[0], acc[1], acc[2], acc[3]};
        *reinterpret_cast<float4*>(otile + w * OS + c0) = o4;
    }
    __syncthreads();

    // coalesced [B,C,N] write: thread t -> (c = t>>3, n = pt0%N + (t&7))
    {
        int c  = t >> 3;
        int nn = t & 7;
        out[(size_t)b * C_ * N_ + (size_t)c * N_ + (pt0 - bB) + nn] = otile[nn * OS + c];
    }
}

// ---------------------------------------------------------------------------
extern "C" void kernel_launch(void* const* d_in, const int* in_sizes, int n_in,
                              void* d_out, int out_size, void* d_ws, size_t ws_size,
                              hipStream_t stream)
{
    const float* coord = (const float*)d_in[0];
    const float* q     = (const float*)d_in[1];
    const float* k     = (const float*)d_in[2];
    const int*   nbr   = (const int*)d_in[3];
    const float* wq = (const float*)d_in[4];
    const float* bq = (const float*)d_in[5];
    const float* wk = (const float*)d_in[6];
    const float* bk = (const float*)d_in[7];
    const float* wv = (const float*)d_in[8];
    const float* bv = (const float*)d_in[9];
    const float* p1_w = (const float*)d_in[10];
    const float* p1_b = (const float*)d_in[11];
    const float* p_bn_g = (const float*)d_in[12];
    const float* p_bn_b = (const float*)d_in[13];
    const float* p_bn_m = (const float*)d_in[14];
    const float* p_bn_v = (const float*)d_in[15];
    const float* p2_w = (const float*)d_in[16];
    const float* p2_b = (const float*)d_in[17];
    const float* w_bn1_g = (const float*)d_in[18];
    const float* w_bn1_b = (const float*)d_in[19];
    const float* w_bn1_m = (const float*)d_in[20];
    const float* w_bn1_v = (const float*)d_in[21];
    const float* w1_w = (const float*)d_in[22];
    const float* w1_b = (const float*)d_in[23];
    const float* w_bn2_g = (const float*)d_in[24];
    const float* w_bn2_b = (const float*)d_in[25];
    const float* w_bn2_m = (const float*)d_in[26];
    const float* w_bn2_v = (const float*)d_in[27];
    const float* w2_w = (const float*)d_in[28];
    const float* w2_b = (const float*)d_in[29];

    const size_t PTS = (size_t)B_ * N_;        // 40000
    char* wsb = (char*)d_ws;
    unsigned int* kv_t = (unsigned int*)wsb;                    // [PTS][64] u32 (10.24MB)
    unsigned int* xq2  = (unsigned int*)(wsb + PTS * C_ * 4);   // [PTS][32] u32 (5.12MB)
    uint4* a1tab = (uint4*)(wsb + PTS * C_ * 4 + PTS * C_ * 2); // 128 uint4
    uint2* a2tab = (uint2*)(a1tab + 128);                       // 64 uint2
    float* cz    = (float*)(a2tab + 64);                        // 48 f32

    // 2500 proj blocks + 1 table-builder block for attn
    proj_kernel<<<2501, 256, 0, stream>>>(
        q, k, coord, wq, wk, wv, bq, bk, bv,
        p1_w, p1_b, p_bn_g, p_bn_b, p_bn_m, p_bn_v, p2_w, p2_b,
        w_bn1_g, w_bn1_b, w_bn1_m, w_bn1_v,
        w1_w, w1_b, w2_w, w2_b,
        w_bn2_g, w_bn2_b, w_bn2_m, w_bn2_v,
        a1tab, a2tab, cz, xq2, kv_t);

    attn_kernel<<<(B_ * N_) / 8, 512, 0, stream>>>(
        nbr, xq2, kv_t, a1tab, a2tab, cz,
        (float*)d_out);
}

// Round 16
// 44.708 us; speedup vs baseline: 1.3941x; 1.1648x over previous
//
#include <hip/hip_runtime.h>
#include <hip/hip_bf16.h>
#include <math.h>

#define B_ 2
#define N_ 20000
#define C_ 64
#define K_ 16
#define CS_ 16
#define EPS_ 1e-5f

typedef float f32x4_t  __attribute__((ext_vector_type(4)));
typedef short bf16x8_t __attribute__((ext_vector_type(8)));
typedef short bf16x4_t __attribute__((ext_vector_type(4)));

__device__ __forceinline__ unsigned int packbf2(float a, float b)
{
    union { __hip_bfloat162 h; unsigned int u; } cv;
    cv.h = __float22bfloat162_rn(float2{a, b});
    return cv.u;
}
__device__ __forceinline__ float bf_lo(unsigned int w)
{
    return __builtin_bit_cast(float, w << 16);
}
__device__ __forceinline__ float bf_hi(unsigned int w)
{
    return __builtin_bit_cast(float, w & 0xFFFF0000u);
}
__device__ __forceinline__ void wave_fence()
{
    __builtin_amdgcn_wave_barrier();
}

// DPP rotate-reduce over each 16-lane row (VALU pipe, not DS).
__device__ __forceinline__ float row_sum16(float x)
{
    float s = x;
    s += __builtin_bit_cast(float, __builtin_amdgcn_update_dpp(
            0, __builtin_bit_cast(int, s), 0x128, 0xF, 0xF, false)); // row_ror:8
    s += __builtin_bit_cast(float, __builtin_amdgcn_update_dpp(
            0, __builtin_bit_cast(int, s), 0x124, 0xF, 0xF, false)); // row_ror:4
    s += __builtin_bit_cast(float, __builtin_amdgcn_update_dpp(
            0, __builtin_bit_cast(int, s), 0x122, 0xF, 0xF, false)); // row_ror:2
    s += __builtin_bit_cast(float, __builtin_amdgcn_update_dpp(
            0, __builtin_bit_cast(int, s), 0x121, 0xF, 0xF, false)); // row_ror:1
    return s;
}

// ---------------------------------------------------------------------------
// Kernel 0: setup, 6 blocks, disjoint work (R13 exact).
//   wtab[m*512+og*128+half*64+l] (uint4)  bf16 A-frags wq/wk/wv
//   a1tab[half*64+l] (uint4), a2tab[l] (uint2)
//   cz[0..15]=zsc, cz[16..31]=zbi, cz[32..47]=tbi
//   ctab[ch] = {bn1s, bn1s*bq-b1f, bk, bv}   (proj epilogue constants)
//   ptab[ch] = {p2w0, p2w1, p2w2, p2b}       (pos-MLP layer-2 row)
// ---------------------------------------------------------------------------
__global__ __launch_bounds__(256) void setup_kernel(
    const float* __restrict__ wq, const float* __restrict__ wk,
    const float* __restrict__ wv,
    const float* __restrict__ bq, const float* __restrict__ bk,
    const float* __restrict__ bv,
    const float* __restrict__ w1_w, const float* __restrict__ w1_b,
    const float* __restrict__ w2_w, const float* __restrict__ w2_b,
    const float* __restrict__ w_bn1_g, const float* __restrict__ w_bn1_b,
    const float* __restrict__ w_bn1_m, const float* __restrict__ w_bn1_v,
    const float* __restrict__ w_bn2_g, const float* __restrict__ w_bn2_b,
    const float* __restrict__ w_bn2_m, const float* __restrict__ w_bn2_v,
    const float* __restrict__ p2_w, const float* __restrict__ p2_b,
    uint4* __restrict__ wtab, uint4* __restrict__ a1tab,
    uint2* __restrict__ a2tab, float* __restrict__ cz,
    float4* __restrict__ ctab, float4* __restrict__ ptab)
{
    const int t   = threadIdx.x;
    const int blk = blockIdx.x;
    {
        int e = blk * 256 + t;
        int m = e >> 9, rem = e & 511;
        int og = rem >> 7, half = (rem >> 6) & 1, l = rem & 63;
        const float* W = (m == 0) ? wq : ((m == 1) ? wk : wv);
        const float* base = W + (size_t)(og * 16 + (l & 15)) * C_ + half * 32 + (l >> 4) * 8;
        uint4 o;
        o.x = packbf2(base[0], base[1]); o.y = packbf2(base[2], base[3]);
        o.z = packbf2(base[4], base[5]); o.w = packbf2(base[6], base[7]);
        wtab[e] = o;
    }
    if (blk == 0 && t < 128) {
        int half = t >> 6, l = t & 63;
        const float* base = w1_w + (size_t)(l & 15) * C_ + half * 32 + (l >> 4) * 8;
        uint4 o;
        o.x = packbf2(base[0], base[1]); o.y = packbf2(base[2], base[3]);
        o.z = packbf2(base[4], base[5]); o.w = packbf2(base[6], base[7]);
        a1tab[t] = o;
    }
    if (blk == 1 && t < 64) {
        const float* base = w2_w + (t & 15) * 16 + (t >> 4) * 4;
        uint2 o;
        o.x = packbf2(base[0], base[1]); o.y = packbf2(base[2], base[3]);
        a2tab[t] = o;
    }
    if (blk == 2 && t < 16) {
        float s = w_bn2_g[t] * rsqrtf(w_bn2_v[t] + EPS_);
        cz[t]      = s;
        cz[16 + t] = (w1_b[t] - w_bn2_m[t]) * s + w_bn2_b[t];
        cz[32 + t] = w2_b[t];
    }
    if (blk == 3 && t < 64) {
        float s   = w_bn1_g[t] * rsqrtf(w_bn1_v[t] + EPS_);
        float b1f = w_bn1_b[t] - w_bn1_m[t] * s;
        ctab[t] = float4{s, s * bq[t] - b1f, bk[t], bv[t]};
    }
    if (blk == 4 && t < 64) {
        ptab[t] = float4{p2_w[t*3+0], p2_w[t*3+1], p2_w[t*3+2], p2_b[t]};
    }
}

// ---------------------------------------------------------------------------
// Kernel A: projections + positional MLP + bn1 fold, MFMA (R13 exact).
// ---------------------------------------------------------------------------
__global__ __launch_bounds__(256) void proj_kernel(
    const float* __restrict__ q, const float* __restrict__ kin,
    const float* __restrict__ coord,
    const float* __restrict__ p1_w, const float* __restrict__ p1_b,
    const float* __restrict__ p_bn_g, const float* __restrict__ p_bn_b,
    const float* __restrict__ p_bn_m, const float* __restrict__ p_bn_v,
    const uint4* __restrict__ wtab,
    const float4* __restrict__ ctab, const float4* __restrict__ ptab,
    unsigned int* __restrict__ xq2, unsigned int* __restrict__ kv_t)
{
    constexpr int PS = 26;
    __shared__ unsigned int qp[32 * PS];
    __shared__ unsigned int kp[32 * PS];

    const int t   = threadIdx.x;
    const int og  = __builtin_amdgcn_readfirstlane(t >> 6);
    const int l   = t & 63;
    const int col = l & 15;
    const int qd  = l >> 4;
    const int pt0 = blockIdx.x * 16;
    const int pt  = pt0 + col;
    const int b   = pt0 / N_;
    const int n   = pt - b * N_;
    const size_t cb = (size_t)b * C_ * N_ + n;

    // cooperative input tile (each element loaded once per block)
#pragma unroll
    for (int r = 0; r < 2; r++) {
        int cp = (og << 3) + (qd << 1) + r;
        int ci = cp * 2;
        float q0 = q[cb + (size_t)ci * N_];
        float q1 = q[cb + (size_t)(ci + 1) * N_];
        float k0 = kin[cb + (size_t)ci * N_];
        float k1 = kin[cb + (size_t)(ci + 1) * N_];
        qp[cp * PS + col] = packbf2(q0, q1);
        kp[cp * PS + col] = packbf2(k0, k1);
    }

    union bf8u { bf16x8_t v; uint4 u4; };
    bf8u awq[2], awk[2], awv[2];
#pragma unroll
    for (int half = 0; half < 2; half++) {
        awq[half].u4 = wtab[0 * 512 + og * 128 + half * 64 + l];
        awk[half].u4 = wtab[1 * 512 + og * 128 + half * 64 + l];
        awv[half].u4 = wtab[2 * 512 + og * 128 + half * 64 + l];
    }

    __syncthreads();

    union bf8b { bf16x8_t v; unsigned int u[4]; };
    bf8b bq_[2], bk_[2];
#pragma unroll
    for (int half = 0; half < 2; half++) {
#pragma unroll
        for (int i2 = 0; i2 < 4; i2++) {
            int cp = half * 16 + qd * 4 + i2;
            bq_[half].u[i2] = qp[cp * PS + col];
            bk_[half].u[i2] = kp[cp * PS + col];
        }
    }

    f32x4_t uq = {0.f, 0.f, 0.f, 0.f};
    f32x4_t uv = {0.f, 0.f, 0.f, 0.f};
    f32x4_t uk = {0.f, 0.f, 0.f, 0.f};
    uq = __builtin_amdgcn_mfma_f32_16x16x32_bf16(awq[0].v, bq_[0].v, uq, 0, 0, 0);
    uq = __builtin_amdgcn_mfma_f32_16x16x32_bf16(awq[1].v, bq_[1].v, uq, 0, 0, 0);
    uv = __builtin_amdgcn_mfma_f32_16x16x32_bf16(awv[0].v, bq_[0].v, uv, 0, 0, 0);
    uv = __builtin_amdgcn_mfma_f32_16x16x32_bf16(awv[1].v, bq_[1].v, uv, 0, 0, 0);
    uk = __builtin_amdgcn_mfma_f32_16x16x32_bf16(awk[0].v, bk_[0].v, uk, 0, 0, 0);
    uk = __builtin_amdgcn_mfma_f32_16x16x32_bf16(awk[1].v, bk_[1].v, uk, 0, 0, 0);

    // positional MLP layer 1 (wave-uniform weights -> s_loads)
    float pbs[3], pbb[3];
#pragma unroll
    for (int j = 0; j < 3; j++) {
        float s = p_bn_g[j] * rsqrtf(p_bn_v[j] + EPS_);
        pbs[j] = s;
        pbb[j] = (p1_b[j] - p_bn_m[j]) * s + p_bn_b[j];
    }
    float cx = coord[pt * 3 + 0], cy = coord[pt * 3 + 1], cz = coord[pt * 3 + 2];
    float h0 = fmaxf(0.f, (p1_w[0]*cx + p1_w[1]*cy + p1_w[2]*cz) * pbs[0] + pbb[0]);
    float h1 = fmaxf(0.f, (p1_w[3]*cx + p1_w[4]*cy + p1_w[5]*cz) * pbs[1] + pbb[1]);
    float h2 = fmaxf(0.f, (p1_w[6]*cx + p1_w[7]*cy + p1_w[8]*cz) * pbs[2] + pbb[2]);

    // epilogue via tables
    const int ch0 = og * 16 + qd * 4;
    float xv2[4];
    uint4 kvo;
#pragma unroll
    for (int rr = 0; rr < 4; rr++) {
        const float4 ct  = ctab[ch0 + rr];
        const float4 pt4 = ptab[ch0 + rr];
        float pos = fmaf(pt4.x, h0, fmaf(pt4.y, h1, fmaf(pt4.z, h2, pt4.w)));
        xv2[rr]   = fmaf(ct.x, uq[rr], ct.y);
        float kk  = ct.x * (uk[rr] + ct.z + pos);
        float vv  = uv[rr] + ct.w + pos;
        (&kvo.x)[rr] = packbf2(kk, vv);
    }
    uint2 xqo;
    xqo.x = packbf2(xv2[0], xv2[1]);
    xqo.y = packbf2(xv2[2], xv2[3]);
    *reinterpret_cast<uint2*>(xq2 + (size_t)pt * 32 + (ch0 >> 1)) = xqo;
    *reinterpret_cast<uint4*>(kv_t + (size_t)pt * C_ + ch0) = kvo;
}

// ---------------------------------------------------------------------------
// Kernel B: attention via MFMA — R13 exact (coalesced roles, DS-lean).
// Block = 512 thr = 8 waves = 8 points.
// Phase1/3 roles: cquad = l&15 (4 channels c0=4*cquad), kq = l>>4
//   (4 neighbors k = 4*kq+j): lanes 0-15 read ONE neighbor row contiguously
//   -> 4x 256B coalesced segments per gather instruction; 4x ds_write_b64.
// Phase2 roles (al = l&15, qd = l>>4): 2x mfma 16x16x32, bn2/relu in regs,
//   1x mfma 16x16x16; softmax via DPP row_ror rotate-reduce (VALU).
// Phase3: 4x ds_read_b128 sfb rows, shfl_xor(16/32) combine, kq==0 writes.
// LDS 30848B -> 4 blocks/CU = 32 waves/CU (max).
// ---------------------------------------------------------------------------
#define WROW 72          // ushorts per w-tile row (144B)
#define WPN  (K_ * WROW) // 1152 per point
#define SS4  20          // sfb row stride (f32)
#define SPN  (K_ * SS4)  // 320 per point
#define OS   68          // otile row stride (f32)

__global__ __launch_bounds__(512, 8) void attn_kernel(
    const int* __restrict__ nbr,
    const unsigned int* __restrict__ xq2, const unsigned int* __restrict__ kv_t,
    const uint4* __restrict__ a1tab, const uint2* __restrict__ a2tab,
    const float* __restrict__ cz,
    float* __restrict__ out)
{
    __shared__ unsigned short wlds_all[8 * WPN];   // 18432B
    __shared__ float          sfb_all[8 * SPN];    // 10240B
    __shared__ float          otile[8 * OS];       //  2176B

    const int t  = threadIdx.x;
    const int w  = __builtin_amdgcn_readfirstlane(t >> 6);
    const int l  = t & 63;
    const int al = l & 15;          // phase-2 / channel-quad role
    const int qd = l >> 4;          // phase-2 row-quad / neighbor-quad role
    const int cquad = al;           // phase-1/3: 4 channels c0..c0+3
    const int kq    = qd;           // phase-1/3: 4 neighbors 4kq..4kq+3
    const int c0    = cquad * 4;
    const int g0    = c0 & 15;

    const int pt0 = blockIdx.x * 8;       // 5000 blocks; 20000%8==0, no straddle
    const int b   = pt0 / N_;
    const int bB  = b * N_;
    const int bn  = pt0 + w;

    unsigned short* wlds = wlds_all + w * WPN;
    float*          sfb  = sfb_all + w * SPN;

    // ---- phase 1: gather 4 neighbors x 4 channels (dwordx4, 16B/lane) ----
    const int* nb = nbr + (size_t)bn * K_;
    uint4 kvw[4];
#pragma unroll
    for (int j = 0; j < 4; j++) {
        int idx = nb[kq * 4 + j];          // wave-uniform -> s_load
        kvw[j] = *reinterpret_cast<const uint4*>(kv_t + ((size_t)(bB + idx) * C_ + c0));
    }
    const uint2 xqu = *reinterpret_cast<const uint2*>(xq2 + (size_t)bn * 32 + (c0 >> 1));
    const float xqa = bf_lo(xqu.x), xqb = bf_hi(xqu.x);
    const float xqc = bf_lo(xqu.y), xqd = bf_hi(xqu.y);

    // constants from tables
    union bf8u { bf16x8_t v; uint4 u4; };
    union bf4u { bf16x4_t v; uint2 u2; };
    bf8u a1q0, a1q1; bf4u a2q;
    a1q0.u4 = a1tab[l];
    a1q1.u4 = a1tab[64 + l];
    a2q.u2  = a2tab[l];
    const float4 zsc4 = *reinterpret_cast<const float4*>(cz + qd * 4);
    const float4 zbi4 = *reinterpret_cast<const float4*>(cz + 16 + qd * 4);
    const float4 tbi4 = *reinterpret_cast<const float4*>(cz + 32 + qd * 4);

    // w = relu(kvlo - xq2), packed pairs -> one ds_write_b64 per neighbor
#pragma unroll
    for (int j = 0; j < 4; j++) {
        float w0 = fmaxf(0.f, bf_lo(kvw[j].x) - xqa);
        float w1 = fmaxf(0.f, bf_lo(kvw[j].y) - xqb);
        float w2 = fmaxf(0.f, bf_lo(kvw[j].z) - xqc);
        float w3 = fmaxf(0.f, bf_lo(kvw[j].w) - xqd);
        uint2 wpk;
        wpk.x = packbf2(w0, w1);
        wpk.y = packbf2(w2, w3);
        *reinterpret_cast<uint2*>(wlds + (kq * 4 + j) * WROW + c0) = wpk;
    }
    wave_fence();

    // ---- phase 2a: u = w1 @ w^T ----
    const bf16x8_t b0 = *reinterpret_cast<const bf16x8_t*>(wlds + al * WROW + qd * 8);
    const bf16x8_t b1 = *reinterpret_cast<const bf16x8_t*>(wlds + al * WROW + 32 + qd * 8);
    f32x4_t u = {0.f, 0.f, 0.f, 0.f};
    u = __builtin_amdgcn_mfma_f32_16x16x32_bf16(a1q0.v, b0, u, 0, 0, 0);
    u = __builtin_amdgcn_mfma_f32_16x16x32_bf16(a1q1.v, b1, u, 0, 0, 0);

    union { bf16x4_t v; unsigned int u2[2]; } zb;
    {
        float z0 = fmaxf(0.f, u[0] * zsc4.x + zbi4.x);
        float z1 = fmaxf(0.f, u[1] * zsc4.y + zbi4.y);
        float z2 = fmaxf(0.f, u[2] * zsc4.z + zbi4.z);
        float z3 = fmaxf(0.f, u[3] * zsc4.w + zbi4.w);
        zb.u2[0] = packbf2(z0, z1);
        zb.u2[1] = packbf2(z2, z3);
    }

    // ---- phase 2b: t = w2 @ z ----
    f32x4_t t4 = {0.f, 0.f, 0.f, 0.f};
    t4 = __builtin_amdgcn_mfma_f32_16x16x16bf16_1k(a2q.v, zb.v, t4, 0, 0, 0);

    // ---- softmax over neighbors: DPP rotate-reduce (VALU) ----
    float4 sv;
#pragma unroll
    for (int rr = 0; rr < 4; rr++) {
        float e = __expf(t4[rr] + (&tbi4.x)[rr]);   // |t| << 80, no max-sub
        float s = row_sum16(e);
        (&sv.x)[rr] = e * __builtin_amdgcn_rcpf(s);
    }
    *reinterpret_cast<float4*>(sfb + al * SS4 + qd * 4) = sv;  // [k][g] row al
    wave_fence();

    // ---- phase 3: out[c] = sum_k v[k][c] * soft[k][c&15] ----
    float acc[4] = {0.f, 0.f, 0.f, 0.f};
#pragma unroll
    for (int j = 0; j < 4; j++) {
        const float4 sp = *reinterpret_cast<const float4*>(sfb + (kq * 4 + j) * SS4 + g0);
        acc[0] = fmaf(bf_hi(kvw[j].x), sp.x, acc[0]);
        acc[1] = fmaf(bf_hi(kvw[j].y), sp.y, acc[1]);
        acc[2] = fmaf(bf_hi(kvw[j].z), sp.z, acc[2]);
        acc[3] = fmaf(bf_hi(kvw[j].w), sp.w, acc[3]);
    }
#pragma unroll
    for (int i = 0; i < 4; i++) {
        acc[i] += __shfl_xor(acc[i], 16);
        acc[i] += __shfl_xor(acc[i], 32);
    }
    if (kq == 0) {
        float4 o4 = float4{acc[0], acc[1], acc[2], acc[3]};
        *reinterpret_cast<float4*>(otile + w * OS + c0) = o4;
    }
    __syncthreads();

    // coalesced [B,C,N] write: thread t -> (c = t>>3, n = pt0%N + (t&7))
    {
        int c  = t >> 3;
        int nn = t & 7;
        out[(size_t)b * C_ * N_ + (size_t)c * N_ + (pt0 - bB) + nn] = otile[nn * OS + c];
    }
}

// ---------------------------------------------------------------------------
extern "C" void kernel_launch(void* const* d_in, const int* in_sizes, int n_in,
                              void* d_out, int out_size, void* d_ws, size_t ws_size,
                              hipStream_t stream)
{
    const float* coord = (const float*)d_in[0];
    const float* q     = (const float*)d_in[1];
    const float* k     = (const float*)d_in[2];
    const int*   nbr   = (const int*)d_in[3];
    const float* wq = (const float*)d_in[4];
    const float* bq = (const float*)d_in[5];
    const float* wk = (const float*)d_in[6];
    const float* bk = (const float*)d_in[7];
    const float* wv = (const float*)d_in[8];
    const float* bv = (const float*)d_in[9];
    const float* p1_w = (const float*)d_in[10];
    const float* p1_b = (const float*)d_in[11];
    const float* p_bn_g = (const float*)d_in[12];
    const float* p_bn_b = (const float*)d_in[13];
    const float* p_bn_m = (const float*)d_in[14];
    const float* p_bn_v = (const float*)d_in[15];
    const float* p2_w = (const float*)d_in[16];
    const float* p2_b = (const float*)d_in[17];
    const float* w_bn1_g = (const float*)d_in[18];
    const float* w_bn1_b = (const float*)d_in[19];
    const float* w_bn1_m = (const float*)d_in[20];
    const float* w_bn1_v = (const float*)d_in[21];
    const float* w1_w = (const float*)d_in[22];
    const float* w1_b = (const float*)d_in[23];
    const float* w_bn2_g = (const float*)d_in[24];
    const float* w_bn2_b = (const float*)d_in[25];
    const float* w_bn2_m = (const float*)d_in[26];
    const float* w_bn2_v = (const float*)d_in[27];
    const float* w2_w = (const float*)d_in[28];
    const float* w2_b = (const float*)d_in[29];

    const size_t PTS = (size_t)B_ * N_;        // 40000
    char* wsb = (char*)d_ws;
    unsigned int* kv_t = (unsigned int*)wsb;                    // [PTS][64] u32 (10.24MB)
    unsigned int* xq2  = (unsigned int*)(wsb + PTS * C_ * 4);   // [PTS][32] u32 (5.12MB)
    uint4* wtab  = (uint4*)(wsb + PTS * C_ * 4 + PTS * C_ * 2); // 1536 uint4
    uint4* a1tab = wtab + 1536;                                 // 128 uint4
    uint2* a2tab = (uint2*)(a1tab + 128);                       // 64 uint2
    float* cz    = (float*)(a2tab + 64);                        // 48 f32
    float4* ctab = (float4*)(cz + 48);                          // 64 float4
    float4* ptab = ctab + 64;                                   // 64 float4

    setup_kernel<<<6, 256, 0, stream>>>(
        wq, wk, wv, bq, bk, bv, w1_w, w1_b, w2_w, w2_b,
        w_bn1_g, w_bn1_b, w_bn1_m, w_bn1_v,
        w_bn2_g, w_bn2_b, w_bn2_m, w_bn2_v,
        p2_w, p2_b,
        wtab, a1tab, a2tab, cz, ctab, ptab);

    proj_kernel<<<(B_ * N_) / 16, 256, 0, stream>>>(
        q, k, coord,
        p1_w, p1_b, p_bn_g, p_bn_b, p_bn_m, p_bn_v,
        wtab, ctab, ptab, xq2, kv_t);

    attn_kernel<<<(B_ * N_) / 8, 512, 0, stream>>>(
        nbr, xq2, kv_t, a1tab, a2tab, cz,
        (float*)d_out);
}

// Round 17
// 43.796 us; speedup vs baseline: 1.4232x; 1.0208x over previous
//
#include <hip/hip_runtime.h>
#include <hip/hip_bf16.h>
#include <math.h>

#define B_ 2
#define N_ 20000
#define C_ 64
#define K_ 16
#define CS_ 16
#define EPS_ 1e-5f

typedef float f32x4_t  __attribute__((ext_vector_type(4)));
typedef short bf16x8_t __attribute__((ext_vector_type(8)));
typedef short bf16x4_t __attribute__((ext_vector_type(4)));

__device__ __forceinline__ unsigned int packbf2(float a, float b)
{
    union { __hip_bfloat162 h; unsigned int u; } cv;
    cv.h = __float22bfloat162_rn(float2{a, b});
    return cv.u;
}
__device__ __forceinline__ float bf_lo(unsigned int w)
{
    return __builtin_bit_cast(float, w << 16);
}
__device__ __forceinline__ float bf_hi(unsigned int w)
{
    return __builtin_bit_cast(float, w & 0xFFFF0000u);
}
__device__ __forceinline__ void wave_fence()
{
    __builtin_amdgcn_wave_barrier();
}

// DPP rotate-reduce over each 16-lane row (VALU pipe, not DS).
__device__ __forceinline__ float row_sum16(float x)
{
    float s = x;
    s += __builtin_bit_cast(float, __builtin_amdgcn_update_dpp(
            0, __builtin_bit_cast(int, s), 0x128, 0xF, 0xF, false)); // row_ror:8
    s += __builtin_bit_cast(float, __builtin_amdgcn_update_dpp(
            0, __builtin_bit_cast(int, s), 0x124, 0xF, 0xF, false)); // row_ror:4
    s += __builtin_bit_cast(float, __builtin_amdgcn_update_dpp(
            0, __builtin_bit_cast(int, s), 0x122, 0xF, 0xF, false)); // row_ror:2
    s += __builtin_bit_cast(float, __builtin_amdgcn_update_dpp(
            0, __builtin_bit_cast(int, s), 0x121, 0xF, 0xF, false)); // row_ror:1
    return s;
}

// ---------------------------------------------------------------------------
// Kernel 0: setup, 6 blocks, disjoint work (R13 exact).
// ---------------------------------------------------------------------------
__global__ __launch_bounds__(256) void setup_kernel(
    const float* __restrict__ wq, const float* __restrict__ wk,
    const float* __restrict__ wv,
    const float* __restrict__ bq, const float* __restrict__ bk,
    const float* __restrict__ bv,
    const float* __restrict__ w1_w, const float* __restrict__ w1_b,
    const float* __restrict__ w2_w, const float* __restrict__ w2_b,
    const float* __restrict__ w_bn1_g, const float* __restrict__ w_bn1_b,
    const float* __restrict__ w_bn1_m, const float* __restrict__ w_bn1_v,
    const float* __restrict__ w_bn2_g, const float* __restrict__ w_bn2_b,
    const float* __restrict__ w_bn2_m, const float* __restrict__ w_bn2_v,
    const float* __restrict__ p2_w, const float* __restrict__ p2_b,
    uint4* __restrict__ wtab, uint4* __restrict__ a1tab,
    uint2* __restrict__ a2tab, float* __restrict__ cz,
    float4* __restrict__ ctab, float4* __restrict__ ptab)
{
    const int t   = threadIdx.x;
    const int blk = blockIdx.x;
    {
        int e = blk * 256 + t;
        int m = e >> 9, rem = e & 511;
        int og = rem >> 7, half = (rem >> 6) & 1, l = rem & 63;
        const float* W = (m == 0) ? wq : ((m == 1) ? wk : wv);
        const float* base = W + (size_t)(og * 16 + (l & 15)) * C_ + half * 32 + (l >> 4) * 8;
        uint4 o;
        o.x = packbf2(base[0], base[1]); o.y = packbf2(base[2], base[3]);
        o.z = packbf2(base[4], base[5]); o.w = packbf2(base[6], base[7]);
        wtab[e] = o;
    }
    if (blk == 0 && t < 128) {
        int half = t >> 6, l = t & 63;
        const float* base = w1_w + (size_t)(l & 15) * C_ + half * 32 + (l >> 4) * 8;
        uint4 o;
        o.x = packbf2(base[0], base[1]); o.y = packbf2(base[2], base[3]);
        o.z = packbf2(base[4], base[5]); o.w = packbf2(base[6], base[7]);
        a1tab[t] = o;
    }
    if (blk == 1 && t < 64) {
        const float* base = w2_w + (t & 15) * 16 + (t >> 4) * 4;
        uint2 o;
        o.x = packbf2(base[0], base[1]); o.y = packbf2(base[2], base[3]);
        a2tab[t] = o;
    }
    if (blk == 2 && t < 16) {
        float s = w_bn2_g[t] * rsqrtf(w_bn2_v[t] + EPS_);
        cz[t]      = s;
        cz[16 + t] = (w1_b[t] - w_bn2_m[t]) * s + w_bn2_b[t];
        cz[32 + t] = w2_b[t];
    }
    if (blk == 3 && t < 64) {
        float s   = w_bn1_g[t] * rsqrtf(w_bn1_v[t] + EPS_);
        float b1f = w_bn1_b[t] - w_bn1_m[t] * s;
        ctab[t] = float4{s, s * bq[t] - b1f, bk[t], bv[t]};
    }
    if (blk == 4 && t < 64) {
        ptab[t] = float4{p2_w[t*3+0], p2_w[t*3+1], p2_w[t*3+2], p2_b[t]};
    }
}

// ---------------------------------------------------------------------------
// Kernel A: projections + positional MLP + bn1 fold, MFMA (R13 exact).
// ---------------------------------------------------------------------------
__global__ __launch_bounds__(256) void proj_kernel(
    const float* __restrict__ q, const float* __restrict__ kin,
    const float* __restrict__ coord,
    const float* __restrict__ p1_w, const float* __restrict__ p1_b,
    const float* __restrict__ p_bn_g, const float* __restrict__ p_bn_b,
    const float* __restrict__ p_bn_m, const float* __restrict__ p_bn_v,
    const uint4* __restrict__ wtab,
    const float4* __restrict__ ctab, const float4* __restrict__ ptab,
    unsigned int* __restrict__ xq2, unsigned int* __restrict__ kv_t)
{
    constexpr int PS = 26;
    __shared__ unsigned int qp[32 * PS];
    __shared__ unsigned int kp[32 * PS];

    const int t   = threadIdx.x;
    const int og  = __builtin_amdgcn_readfirstlane(t >> 6);
    const int l   = t & 63;
    const int col = l & 15;
    const int qd  = l >> 4;
    const int pt0 = blockIdx.x * 16;
    const int pt  = pt0 + col;
    const int b   = pt0 / N_;
    const int n   = pt - b * N_;
    const size_t cb = (size_t)b * C_ * N_ + n;

#pragma unroll
    for (int r = 0; r < 2; r++) {
        int cp = (og << 3) + (qd << 1) + r;
        int ci = cp * 2;
        float q0 = q[cb + (size_t)ci * N_];
        float q1 = q[cb + (size_t)(ci + 1) * N_];
        float k0 = kin[cb + (size_t)ci * N_];
        float k1 = kin[cb + (size_t)(ci + 1) * N_];
        qp[cp * PS + col] = packbf2(q0, q1);
        kp[cp * PS + col] = packbf2(k0, k1);
    }

    union bf8u { bf16x8_t v; uint4 u4; };
    bf8u awq[2], awk[2], awv[2];
#pragma unroll
    for (int half = 0; half < 2; half++) {
        awq[half].u4 = wtab[0 * 512 + og * 128 + half * 64 + l];
        awk[half].u4 = wtab[1 * 512 + og * 128 + half * 64 + l];
        awv[half].u4 = wtab[2 * 512 + og * 128 + half * 64 + l];
    }

    __syncthreads();

    union bf8b { bf16x8_t v; unsigned int u[4]; };
    bf8b bq_[2], bk_[2];
#pragma unroll
    for (int half = 0; half < 2; half++) {
#pragma unroll
        for (int i2 = 0; i2 < 4; i2++) {
            int cp = half * 16 + qd * 4 + i2;
            bq_[half].u[i2] = qp[cp * PS + col];
            bk_[half].u[i2] = kp[cp * PS + col];
        }
    }

    f32x4_t uq = {0.f, 0.f, 0.f, 0.f};
    f32x4_t uv = {0.f, 0.f, 0.f, 0.f};
    f32x4_t uk = {0.f, 0.f, 0.f, 0.f};
    uq = __builtin_amdgcn_mfma_f32_16x16x32_bf16(awq[0].v, bq_[0].v, uq, 0, 0, 0);
    uq = __builtin_amdgcn_mfma_f32_16x16x32_bf16(awq[1].v, bq_[1].v, uq, 0, 0, 0);
    uv = __builtin_amdgcn_mfma_f32_16x16x32_bf16(awv[0].v, bq_[0].v, uv, 0, 0, 0);
    uv = __builtin_amdgcn_mfma_f32_16x16x32_bf16(awv[1].v, bq_[1].v, uv, 0, 0, 0);
    uk = __builtin_amdgcn_mfma_f32_16x16x32_bf16(awk[0].v, bk_[0].v, uk, 0, 0, 0);
    uk = __builtin_amdgcn_mfma_f32_16x16x32_bf16(awk[1].v, bk_[1].v, uk, 0, 0, 0);

    float pbs[3], pbb[3];
#pragma unroll
    for (int j = 0; j < 3; j++) {
        float s = p_bn_g[j] * rsqrtf(p_bn_v[j] + EPS_);
        pbs[j] = s;
        pbb[j] = (p1_b[j] - p_bn_m[j]) * s + p_bn_b[j];
    }
    float cx = coord[pt * 3 + 0], cy = coord[pt * 3 + 1], cz = coord[pt * 3 + 2];
    float h0 = fmaxf(0.f, (p1_w[0]*cx + p1_w[1]*cy + p1_w[2]*cz) * pbs[0] + pbb[0]);
    float h1 = fmaxf(0.f, (p1_w[3]*cx + p1_w[4]*cy + p1_w[5]*cz) * pbs[1] + pbb[1]);
    float h2 = fmaxf(0.f, (p1_w[6]*cx + p1_w[7]*cy + p1_w[8]*cz) * pbs[2] + pbb[2]);

    const int ch0 = og * 16 + qd * 4;
    float xv2[4];
    uint4 kvo;
#pragma unroll
    for (int rr = 0; rr < 4; rr++) {
        const float4 ct  = ctab[ch0 + rr];
        const float4 pt4 = ptab[ch0 + rr];
        float pos = fmaf(pt4.x, h0, fmaf(pt4.y, h1, fmaf(pt4.z, h2, pt4.w)));
        xv2[rr]   = fmaf(ct.x, uq[rr], ct.y);
        float kk  = ct.x * (uk[rr] + ct.z + pos);
        float vv  = uv[rr] + ct.w + pos;
        (&kvo.x)[rr] = packbf2(kk, vv);
    }
    uint2 xqo;
    xqo.x = packbf2(xv2[0], xv2[1]);
    xqo.y = packbf2(xv2[2], xv2[3]);
    *reinterpret_cast<uint2*>(xq2 + (size_t)pt * 32 + (ch0 >> 1)) = xqo;
    *reinterpret_cast<uint4*>(kv_t + (size_t)pt * C_ + ch0) = kvo;
}

// ---------------------------------------------------------------------------
// Kernel B: attention via MFMA — R13 structure + XCD-aware batch partition.
// Blocks dispatch round-robin over 8 XCDs (blockIdx % 8). Map XCDs 0-3 ->
// batch 0, XCDs 4-7 -> batch 1, so each XCD's random-gather working set is
// ONE batch's 5.12MB kv_t (vs 10.24MB) — closer to its 4MB private L2.
// 5000 % 8 == 0 -> bijective; each XCD still gets contiguous point ranges.
// All other structure identical to R13/R16.
// ---------------------------------------------------------------------------
#define WROW 72          // ushorts per w-tile row (144B)
#define WPN  (K_ * WROW) // 1152 per point
#define SS4  20          // sfb row stride (f32)
#define SPN  (K_ * SS4)  // 320 per point
#define OS   68          // otile row stride (f32)

__global__ __launch_bounds__(512, 8) void attn_kernel(
    const int* __restrict__ nbr,
    const unsigned int* __restrict__ xq2, const unsigned int* __restrict__ kv_t,
    const uint4* __restrict__ a1tab, const uint2* __restrict__ a2tab,
    const float* __restrict__ cz,
    float* __restrict__ out)
{
    __shared__ unsigned short wlds_all[8 * WPN];   // 18432B
    __shared__ float          sfb_all[8 * SPN];    // 10240B
    __shared__ float          otile[8 * OS];       //  2176B

    const int t  = threadIdx.x;
    const int w  = __builtin_amdgcn_readfirstlane(t >> 6);
    const int l  = t & 63;
    const int al = l & 15;          // phase-2 / channel-quad role
    const int qd = l >> 4;          // phase-2 row-quad / neighbor-quad role
    const int cquad = al;           // phase-1/3: 4 channels c0..c0+3
    const int kq    = qd;           // phase-1/3: 4 neighbors 4kq..4kq+3
    const int c0    = cquad * 4;
    const int g0    = c0 & 15;

    // XCD-aware batch partition: r = XCD slot, b = r>>2 picks the batch,
    // chunk = (r&3)*625 + (i>>3) walks contiguous 8-point tiles per XCD.
    const int i  = blockIdx.x;                // 5000 blocks, %8 == 0
    const int r  = i & 7;
    const int jj = i >> 3;                    // 0..624
    const int b  = r >> 2;                    // batch (XCDs 0-3 -> 0, 4-7 -> 1)
    const int chunk = (r & 3) * 625 + jj;     // 0..2499 within batch
    const int bB  = b * N_;
    const int pt0 = bB + chunk * 8;           // no batch straddle (N%8==0)
    const int bn  = pt0 + w;

    unsigned short* wlds = wlds_all + w * WPN;
    float*          sfb  = sfb_all + w * SPN;

    // ---- phase 1: gather 4 neighbors x 4 channels (dwordx4, 16B/lane) ----
    const int* nb = nbr + (size_t)bn * K_;
    uint4 kvw[4];
#pragma unroll
    for (int j = 0; j < 4; j++) {
        int idx = nb[kq * 4 + j];          // wave-uniform -> s_load
        kvw[j] = *reinterpret_cast<const uint4*>(kv_t + ((size_t)(bB + idx) * C_ + c0));
    }
    const uint2 xqu = *reinterpret_cast<const uint2*>(xq2 + (size_t)bn * 32 + (c0 >> 1));
    const float xqa = bf_lo(xqu.x), xqb = bf_hi(xqu.x);
    const float xqc = bf_lo(xqu.y), xqd = bf_hi(xqu.y);

    // constants from tables
    union bf8u { bf16x8_t v; uint4 u4; };
    union bf4u { bf16x4_t v; uint2 u2; };
    bf8u a1q0, a1q1; bf4u a2q;
    a1q0.u4 = a1tab[l];
    a1q1.u4 = a1tab[64 + l];
    a2q.u2  = a2tab[l];
    const float4 zsc4 = *reinterpret_cast<const float4*>(cz + qd * 4);
    const float4 zbi4 = *reinterpret_cast<const float4*>(cz + 16 + qd * 4);
    const float4 tbi4 = *reinterpret_cast<const float4*>(cz + 32 + qd * 4);

    // w = relu(kvlo - xq2), packed pairs -> one ds_write_b64 per neighbor
#pragma unroll
    for (int j = 0; j < 4; j++) {
        float w0 = fmaxf(0.f, bf_lo(kvw[j].x) - xqa);
        float w1 = fmaxf(0.f, bf_lo(kvw[j].y) - xqb);
        float w2 = fmaxf(0.f, bf_lo(kvw[j].z) - xqc);
        float w3 = fmaxf(0.f, bf_lo(kvw[j].w) - xqd);
        uint2 wpk;
        wpk.x = packbf2(w0, w1);
        wpk.y = packbf2(w2, w3);
        *reinterpret_cast<uint2*>(wlds + (kq * 4 + j) * WROW + c0) = wpk;
    }
    wave_fence();

    // ---- phase 2a: u = w1 @ w^T ----
    const bf16x8_t b0 = *reinterpret_cast<const bf16x8_t*>(wlds + al * WROW + qd * 8);
    const bf16x8_t b1 = *reinterpret_cast<const bf16x8_t*>(wlds + al * WROW + 32 + qd * 8);
    f32x4_t u = {0.f, 0.f, 0.f, 0.f};
    u = __builtin_amdgcn_mfma_f32_16x16x32_bf16(a1q0.v, b0, u, 0, 0, 0);
    u = __builtin_amdgcn_mfma_f32_16x16x32_bf16(a1q1.v, b1, u, 0, 0, 0);

    union { bf16x4_t v; unsigned int u2[2]; } zb;
    {
        float z0 = fmaxf(0.f, u[0] * zsc4.x + zbi4.x);
        float z1 = fmaxf(0.f, u[1] * zsc4.y + zbi4.y);
        float z2 = fmaxf(0.f, u[2] * zsc4.z + zbi4.z);
        float z3 = fmaxf(0.f, u[3] * zsc4.w + zbi4.w);
        zb.u2[0] = packbf2(z0, z1);
        zb.u2[1] = packbf2(z2, z3);
    }

    // ---- phase 2b: t = w2 @ z ----
    f32x4_t t4 = {0.f, 0.f, 0.f, 0.f};
    t4 = __builtin_amdgcn_mfma_f32_16x16x16bf16_1k(a2q.v, zb.v, t4, 0, 0, 0);

    // ---- softmax over neighbors: DPP rotate-reduce (VALU) ----
    float4 sv;
#pragma unroll
    for (int rr = 0; rr < 4; rr++) {
        float e = __expf(t4[rr] + (&tbi4.x)[rr]);   // |t| << 80, no max-sub
        float s = row_sum16(e);
        (&sv.x)[rr] = e * __builtin_amdgcn_rcpf(s);
    }
    *reinterpret_cast<float4*>(sfb + al * SS4 + qd * 4) = sv;  // [k][g] row al
    wave_fence();

    // ---- phase 3: out[c] = sum_k v[k][c] * soft[k][c&15] ----
    float acc[4] = {0.f, 0.f, 0.f, 0.f};
#pragma unroll
    for (int j = 0; j < 4; j++) {
        const float4 sp = *reinterpret_cast<const float4*>(sfb + (kq * 4 + j) * SS4 + g0);
        acc[0] = fmaf(bf_hi(kvw[j].x), sp.x, acc[0]);
        acc[1] = fmaf(bf_hi(kvw[j].y), sp.y, acc[1]);
        acc[2] = fmaf(bf_hi(kvw[j].z), sp.z, acc[2]);
        acc[3] = fmaf(bf_hi(kvw[j].w), sp.w, acc[3]);
    }
#pragma unroll
    for (int ii = 0; ii < 4; ii++) {
        acc[ii] += __shfl_xor(acc[ii], 16);
        acc[ii] += __shfl_xor(acc[ii], 32);
    }
    if (kq == 0) {
        float4 o4 = float4{acc[0], acc[1], acc[2], acc[3]};
        *reinterpret_cast<float4*>(otile + w * OS + c0) = o4;
    }
    __syncthreads();

    // coalesced [B,C,N] write: thread t -> (c = t>>3, n = (pt0-bB) + (t&7))
    {
        int c  = t >> 3;
        int nn = t & 7;
        out[(size_t)b * C_ * N_ + (size_t)c * N_ + (pt0 - bB) + nn] = otile[nn * OS + c];
    }
}

// ---------------------------------------------------------------------------
extern "C" void kernel_launch(void* const* d_in, const int* in_sizes, int n_in,
                              void* d_out, int out_size, void* d_ws, size_t ws_size,
                              hipStream_t stream)
{
    const float* coord = (const float*)d_in[0];
    const float* q     = (const float*)d_in[1];
    const float* k     = (const float*)d_in[2];
    const int*   nbr   = (const int*)d_in[3];
    const float* wq = (const float*)d_in[4];
    const float* bq = (const float*)d_in[5];
    const float* wk = (const float*)d_in[6];
    const float* bk = (const float*)d_in[7];
    const float* wv = (const float*)d_in[8];
    const float* bv = (const float*)d_in[9];
    const float* p1_w = (const float*)d_in[10];
    const float* p1_b = (const float*)d_in[11];
    const float* p_bn_g = (const float*)d_in[12];
    const float* p_bn_b = (const float*)d_in[13];
    const float* p_bn_m = (const float*)d_in[14];
    const float* p_bn_v = (const float*)d_in[15];
    const float* p2_w = (const float*)d_in[16];
    const float* p2_b = (const float*)d_in[17];
    const float* w_bn1_g = (const float*)d_in[18];
    const float* w_bn1_b = (const float*)d_in[19];
    const float* w_bn1_m = (const float*)d_in[20];
    const float* w_bn1_v = (const float*)d_in[21];
    const float* w1_w = (const float*)d_in[22];
    const float* w1_b = (const float*)d_in[23];
    const float* w_bn2_g = (const float*)d_in[24];
    const float* w_bn2_b = (const float*)d_in[25];
    const float* w_bn2_m = (const float*)d_in[26];
    const float* w_bn2_v = (const float*)d_in[27];
    const float* w2_w = (const float*)d_in[28];
    const float* w2_b = (const float*)d_in[29];

    const size_t PTS = (size_t)B_ * N_;        // 40000
    char* wsb = (char*)d_ws;
    unsigned int* kv_t = (unsigned int*)wsb;                    // [PTS][64] u32 (10.24MB)
    unsigned int* xq2  = (unsigned int*)(wsb + PTS * C_ * 4);   // [PTS][32] u32 (5.12MB)
    uint4* wtab  = (uint4*)(wsb + PTS * C_ * 4 + PTS * C_ * 2); // 1536 uint4
    uint4* a1tab = wtab + 1536;                                 // 128 uint4
    uint2* a2tab = (uint2*)(a1tab + 128);                       // 64 uint2
    float* cz    = (float*)(a2tab + 64);                        // 48 f32
    float4* ctab = (float4*)(cz + 48);                          // 64 float4
    float4* ptab = ctab + 64;                                   // 64 float4

    setup_kernel<<<6, 256, 0, stream>>>(
        wq, wk, wv, bq, bk, bv, w1_w, w1_b, w2_w, w2_b,
        w_bn1_g, w_bn1_b, w_bn1_m, w_bn1_v,
        w_bn2_g, w_bn2_b, w_bn2_m, w_bn2_v,
        p2_w, p2_b,
        wtab, a1tab, a2tab, cz, ctab, ptab);

    proj_kernel<<<(B_ * N_) / 16, 256, 0, stream>>>(
        q, k, coord,
        p1_w, p1_b, p_bn_g, p_bn_b, p_bn_m, p_bn_v,
        wtab, ctab, ptab, xq2, kv_t);

    attn_kernel<<<(B_ * N_) / 8, 512, 0, stream>>>(
        nbr, xq2, kv_t, a1tab, a2tab, cz,
        (float*)d_out);
}